// Round 7
// baseline (857.083 us; speedup 1.0000x reference)
//
#include <hip/hip_runtime.h>
#include <hip/hip_cooperative_groups.h>
#include <stdint.h>

namespace cg = cooperative_groups;

#define HID 256
#define NMAXPIX (1025 * 1025)
#define NREP 8    // histogram replicas, replica-major: hist[rep*NB + bin]
#define NSEG 2048 // selection segments

// per-stage small-buffer layout (u32 units)
#define HISTA_OFF 0          // 8 x 2048
#define HISTB_OFF 16384      // 8 x 2048
#define HISTC_OFF 32768      // 8 x 1024
#define GTC_OFF   40960      // 2048
#define TIC_OFF   43008      // 2048
#define STAGE_U32 45056

// ---------------- MLP eval (single point), float4 LDS weight reads ----------------
__device__ __forceinline__ float mlp_eval4(float wx, float wy,
                                           const float4* __restrict__ w1x,
                                           const float4* __restrict__ w1y,
                                           const float4* __restrict__ vb1,
                                           const float4* __restrict__ vw2, float b2v) {
    const float C0 = (float)(0.5 / 1025.0);
    float px = (wx / 1025.0f + C0) * 2.0f - 1.0f;
    float py = (wy / 1025.0f + C0) * 2.0f - 1.0f;
    float a0 = 0.f, a1 = 0.f, a2 = 0.f, a3 = 0.f;
#pragma unroll 8
    for (int q = 0; q < HID / 4; ++q) {
        float4 a = w1x[q], b = w1y[q], c = vb1[q], d = vw2[q];
        float h0 = px * a.x + py * b.x + c.x;
        float h1 = px * a.y + py * b.y + c.y;
        float h2 = px * a.z + py * b.z + c.z;
        float h3 = px * a.w + py * b.w + c.w;
        h0 = h0 > 0.f ? h0 : 0.f;
        h1 = h1 > 0.f ? h1 : 0.f;
        h2 = h2 > 0.f ? h2 : 0.f;
        h3 = h3 > 0.f ? h3 : 0.f;
        a0 += h0 * d.x;
        a1 += h1 * d.y;
        a2 += h2 * d.z;
        a3 += h3 * d.w;
    }
    float x = ((a0 + a1) + (a2 + a3)) + b2v;
    float r;
    if (x >= 0.f) { r = 1.0f / (1.0f + expf(-x)); }
    else { float e = expf(x); r = e / (1.0f + e); }
    return r;
}

// ---------------- block exclusive scan helper (256 threads) ----------------
__device__ __forceinline__ uint32_t block_exscan_256(uint32_t v, volatile uint32_t* lds4) {
    int lane = threadIdx.x & 63, w = threadIdx.x >> 6;
    uint32_t inc = v;
#pragma unroll
    for (int d = 1; d < 64; d <<= 1) {
        uint32_t o = (uint32_t)__shfl_up((int)inc, d, 64);
        if (lane >= d) inc += o;
    }
    if (lane == 63) lds4[w] = inc;
    __syncthreads();
    uint32_t woff = 0;
    for (int i = 0; i < w; ++i) woff += lds4[i];
    return woff + inc - v;
}

// ---------------- redundant per-block radix scan (every block computes the same result) ----------------
__device__ void scan_dev(const uint32_t* __restrict__ hist, int NB,
                         uint32_t rem_in, uint32_t prefix_in, int shift,
                         uint32_t* outp, uint32_t* outr,
                         volatile uint32_t* lds4, volatile uint32_t* ldspair) {
    int tid = threadIdx.x;
    __syncthreads();  // protect lds4/ldspair reuse across phases
    int C = NB >> 8;                 // 8 (NB=2048) or 4 (NB=1024)
    int b0 = NB - (tid + 1) * C;     // thread 0 owns top bins
    uint32_t cnts[8];
#pragma unroll
    for (int k = 0; k < 8; ++k) cnts[k] = 0;
    for (int rep = 0; rep < NREP; ++rep) {
        const uint4* p = (const uint4*)(hist + (size_t)rep * NB + b0);
#pragma unroll
        for (int g = 0; g < 2; ++g) {
            if (g * 4 < C) {
                uint4 v = p[g];
                cnts[g * 4 + 0] += v.x;
                cnts[g * 4 + 1] += v.y;
                cnts[g * 4 + 2] += v.z;
                cnts[g * 4 + 3] += v.w;
            }
        }
    }
    uint32_t ssum = 0;
    for (int k = 0; k < C; ++k) ssum += cnts[k];
    uint32_t excl = block_exscan_256(ssum, (volatile uint32_t*)lds4);
    uint32_t run = excl;
    for (int k = 0; k < C; ++k) {
        uint32_t c = cnts[C - 1 - k];   // descending bin order within thread
        if (rem_in > run && rem_in <= run + c) {
            ldspair[0] = (prefix_in << shift) | (uint32_t)(b0 + C - 1 - k);
            ldspair[1] = rem_in - run;
        }
        run += c;
    }
    __syncthreads();
    *outp = ldspair[0];
    *outr = ldspair[1];
}

// ---------------- the whole pipeline as ONE cooperative kernel ----------------
__global__ __launch_bounds__(256, 2) void k_all(
    const float* __restrict__ w1, const float* __restrict__ b1,
    const float* __restrict__ w2, const float* __restrict__ b2,
    float* __restrict__ buf0, float* __restrict__ buf1,
    uint32_t* __restrict__ keys, uint32_t* __restrict__ smallb,
    uint32_t* __restrict__ outlist, float* __restrict__ out) {
    cg::grid_group g_grid = cg::this_grid();
    __shared__ alignas(16) float sw1[2 * HID];
    __shared__ alignas(16) float sb1[HID];
    __shared__ alignas(16) float sw2[HID];
    __shared__ uint32_t hist[2048];
    __shared__ uint32_t lds4[4];
    __shared__ uint32_t ldspair[2];

    int tid = threadIdx.x, lane = tid & 63;
    int gtid = blockIdx.x * 256 + tid;
    int nthreads = gridDim.x * 256;
    int gw = gtid >> 6;
    int totw = nthreads >> 6;

    for (int i = tid; i < 2 * HID; i += 256) sw1[i] = w1[i];
    sb1[tid] = b1[tid];
    sw2[tid] = w2[tid];
    float vb2 = b2[0];
    __syncthreads();
    const float4* w1x = (const float4*)sw1;
    const float4* w1y = (const float4*)(sw1 + HID);
    const float4* vb1 = (const float4*)sb1;
    const float4* vw2 = (const float4*)sw2;
    const float C0 = (float)(0.5 / 1025.0);

    // ---- phase 0: zero hist/count buffers + dense 65x65 eval ----
    for (int i = gtid; i < 4 * STAGE_U32; i += nthreads) smallb[i] = 0;
    for (int n = gtid; n < 65 * 65; n += nthreads) {
        int i = n / 65, j = n % 65;
        buf0[n] = mlp_eval4(16.0f * (float)j, 16.0f * (float)i, w1x, w1y, vb1, vw2, vb2);
    }
    g_grid.sync();

    float* cur = buf0;
    float* nxt = buf1;
    const int resA[5] = {65, 129, 257, 513, 1025};
    const int nptA[5] = {0, 4096, 16384, 65536, 262144};

    for (int s = 1; s < 5; ++s) {
        int rp = resA[s - 1], r = resA[s];
        int N = r * r;
        uint32_t npt = (uint32_t)nptA[s];
        uint32_t* sm    = smallb + (size_t)(s - 1) * STAGE_U32;
        uint32_t* histA = sm + HISTA_OFF;
        uint32_t* histB = sm + HISTB_OFF;
        uint32_t* histC = sm + HISTC_OFF;
        uint32_t* gtc   = sm + GTC_OFF;
        uint32_t* tic   = sm + TIC_OFF;
        int seglen = (N + NSEG - 1) / NSEG;
        float stride = 1024.0f / (float)(r - 1);

        // ---- phase A: upsample 2x (dyadic averages) + key + msb-11 histogram ----
        for (int k = tid; k < 2048; k += 256) hist[k] = 0;
        __syncthreads();
        for (int n0 = blockIdx.x * 256; n0 < N; n0 += nthreads) {
            int n = n0 + tid;
            bool act = n < N;
            uint32_t key = 0;
            if (act) {
                int i = n / r, j = n % r;
                int i2 = i >> 1, j2 = j >> 1;
                float v;
                if ((i & 1) == 0) {
                    if ((j & 1) == 0) {
                        v = cur[i2 * rp + j2];
                    } else {
                        float a = cur[i2 * rp + j2], b = cur[i2 * rp + j2 + 1];
                        v = a * 0.5f + b * 0.5f;
                    }
                } else {
                    if ((j & 1) == 0) {
                        float a = cur[i2 * rp + j2], b = cur[(i2 + 1) * rp + j2];
                        v = a * 0.5f + b * 0.5f;
                    } else {
                        float a = cur[i2 * rp + j2],       c = cur[i2 * rp + j2 + 1];
                        float b = cur[(i2 + 1) * rp + j2], d = cur[(i2 + 1) * rp + j2 + 1];
                        float t1 = a * 0.5f + b * 0.5f;
                        float t2 = c * 0.5f + d * 0.5f;
                        v = t1 * 0.5f + t2 * 0.5f;
                    }
                }
                nxt[n] = v;
                float unc = -fabsf(v - 0.5f);
                uint32_t u = __float_as_uint(unc);
                key = (u & 0x80000000u) ? ~u : (u | 0x80000000u);
                keys[n] = key;
            }
            uint32_t bin = key >> 21;
            unsigned long long m = __ballot(act);
            if (m) {
                int leader = __ffsll(m) - 1;
                uint32_t lbin = (uint32_t)__shfl((int)bin, leader, 64);
                unsigned long long smk = __ballot(act && bin == lbin);
                if (smk == m) {
                    if (lane == leader) atomicAdd(&hist[lbin], (uint32_t)__popcll(m));
                } else if (act) {
                    atomicAdd(&hist[bin], 1u);
                }
            }
        }
        __syncthreads();
        {
            uint32_t* myrep = histA + (size_t)(blockIdx.x & (NREP - 1)) * 2048;
            for (int k = tid; k < 2048; k += 256) {
                uint32_t c = hist[k];
                if (c) atomicAdd(&myrep[k], c);
            }
        }
        g_grid.sync();

        // ---- phase B: redundant scan of histA; filtered mid-11 histogram ----
        uint32_t pfx, rem;
        scan_dev(histA, 2048, npt, 0u, 0, &pfx, &rem, lds4, ldspair);
        __syncthreads();
        for (int k = tid; k < 2048; k += 256) hist[k] = 0;
        __syncthreads();
        for (int n0 = blockIdx.x * 256; n0 < N; n0 += nthreads) {
            int n = n0 + tid;
            bool inb = n < N;
            uint32_t key = inb ? keys[n] : 0u;
            bool flt = inb && ((key >> 21) == pfx);
            uint32_t bin = (key >> 10) & 0x7FFu;
            unsigned long long m = __ballot(flt);
            if (m) {
                int leader = __ffsll(m) - 1;
                uint32_t lbin = (uint32_t)__shfl((int)bin, leader, 64);
                unsigned long long smk = __ballot(flt && bin == lbin);
                if (smk == m) {
                    if (lane == leader) atomicAdd(&hist[lbin], (uint32_t)__popcll(m));
                } else if (flt) {
                    atomicAdd(&hist[bin], 1u);
                }
            }
        }
        __syncthreads();
        {
            uint32_t* myrep = histB + (size_t)(blockIdx.x & (NREP - 1)) * 2048;
            for (int k = tid; k < 2048; k += 256) {
                uint32_t c = hist[k];
                if (c) atomicAdd(&myrep[k], c);
            }
        }
        g_grid.sync();

        // ---- phase C: redundant scan of histB; filtered low-10 histogram ----
        scan_dev(histB, 2048, rem, pfx, 11, &pfx, &rem, lds4, ldspair);
        __syncthreads();
        for (int k = tid; k < 2048; k += 256) hist[k] = 0;
        __syncthreads();
        for (int n0 = blockIdx.x * 256; n0 < N; n0 += nthreads) {
            int n = n0 + tid;
            bool inb = n < N;
            uint32_t key = inb ? keys[n] : 0u;
            bool flt = inb && ((key >> 10) == pfx);
            uint32_t bin = key & 0x3FFu;
            unsigned long long m = __ballot(flt);
            if (m) {
                int leader = __ffsll(m) - 1;
                uint32_t lbin = (uint32_t)__shfl((int)bin, leader, 64);
                unsigned long long smk = __ballot(flt && bin == lbin);
                if (smk == m) {
                    if (lane == leader) atomicAdd(&hist[lbin], (uint32_t)__popcll(m));
                } else if (flt) {
                    atomicAdd(&hist[bin], 1u);
                }
            }
        }
        __syncthreads();
        {
            uint32_t* myrep = histC + (size_t)(blockIdx.x & (NREP - 1)) * 1024;
            for (int k = tid; k < 1024; k += 256) {
                uint32_t c = hist[k];
                if (c) atomicAdd(&myrep[k], c);
            }
        }
        g_grid.sync();

        // ---- phase D: redundant scan of histC -> (K, t); per-segment gt/tie counts ----
        uint32_t K, t;
        scan_dev(histC, 1024, rem, pfx, 10, &K, &t, lds4, ldspair);
        for (int wv = gw; wv < NSEG; wv += totw) {
            int s0 = wv * seglen;
            int s1 = s0 + seglen; if (s1 > N) s1 = N;
            uint32_t gcnt = 0, tcnt = 0;
            for (int base = s0; base < s1; base += 64) {
                int n = base + lane;
                if (n < s1) {
                    uint32_t k = keys[n];
                    gcnt += (k > K) ? 1u : 0u;
                    tcnt += (k == K) ? 1u : 0u;
                }
            }
#pragma unroll
            for (int d = 32; d; d >>= 1) {
                gcnt += (uint32_t)__shfl_down((int)gcnt, d, 64);
                tcnt += (uint32_t)__shfl_down((int)tcnt, d, 64);
            }
            if (lane == 0) { gtc[wv] = gcnt; tic[wv] = tcnt; }
        }
        g_grid.sync();

        // ---- phase E: atomic-free compaction (exact top-k, index-ascending ties) ----
        for (int wv = gw; wv < NSEG; wv += totw) {
            uint32_t gp = 0, tp = 0;
            for (int i = lane; i < wv; i += 64) { gp += gtc[i]; tp += tic[i]; }
#pragma unroll
            for (int d = 32; d; d >>= 1) {
                gp += (uint32_t)__shfl_down((int)gp, d, 64);
                tp += (uint32_t)__shfl_down((int)tp, d, 64);
            }
            gp = (uint32_t)__shfl((int)gp, 0, 64);
            tp = (uint32_t)__shfl((int)tp, 0, 64);
            uint32_t acc_tie_before = tp < t ? tp : t;
            uint32_t outbase = gp + acc_tie_before;
            uint32_t tie_run = tp;
            int s0 = wv * seglen;
            int s1 = s0 + seglen; if (s1 > N) s1 = N;
            unsigned long long lowmask = (lane == 63) ? ~0ull >> 1 : ((1ull << lane) - 1ull);
            for (int base = s0; base < s1; base += 64) {
                int n = base + lane;
                bool inb = n < s1;
                uint32_t key = inb ? keys[n] : 0u;
                bool gt = inb && (key > K);
                bool tie = inb && (key == K);
                unsigned long long tm = __ballot(tie);
                uint32_t trank = tie_run + (uint32_t)__popcll(tm & lowmask);
                bool sel = gt || (tie && trank < t);
                unsigned long long smk = __ballot(sel);
                if (sel) outlist[outbase + (uint32_t)__popcll(smk & lowmask)] = (uint32_t)n;
                outbase += (uint32_t)__popcll(smk);
                tie_run += (uint32_t)__popcll(tm);
            }
        }
        g_grid.sync();

        // ---- phase F: dense eval of compacted list (4 points per weight read) ----
        int nq = (int)(npt >> 2);
        for (int q = gtid; q < nq; q += nthreads) {
            uint4 nn = ((const uint4*)outlist)[q];
            uint32_t n0 = nn.x, n1 = nn.y, n2 = nn.z, n3 = nn.w;
            float px0, py0, px1, py1, px2, py2, px3, py3;
            {
                int i0 = (int)n0 / r, j0 = (int)n0 % r;
                int i1 = (int)n1 / r, j1 = (int)n1 % r;
                int i2 = (int)n2 / r, j2 = (int)n2 % r;
                int i3 = (int)n3 / r, j3 = (int)n3 % r;
                px0 = ((stride * (float)j0) / 1025.0f + C0) * 2.0f - 1.0f;
                py0 = ((stride * (float)i0) / 1025.0f + C0) * 2.0f - 1.0f;
                px1 = ((stride * (float)j1) / 1025.0f + C0) * 2.0f - 1.0f;
                py1 = ((stride * (float)i1) / 1025.0f + C0) * 2.0f - 1.0f;
                px2 = ((stride * (float)j2) / 1025.0f + C0) * 2.0f - 1.0f;
                py2 = ((stride * (float)i2) / 1025.0f + C0) * 2.0f - 1.0f;
                px3 = ((stride * (float)j3) / 1025.0f + C0) * 2.0f - 1.0f;
                py3 = ((stride * (float)i3) / 1025.0f + C0) * 2.0f - 1.0f;
            }
            float4 A0 = {0, 0, 0, 0}, A1 = {0, 0, 0, 0}, A2 = {0, 0, 0, 0}, A3 = {0, 0, 0, 0};
#pragma unroll 4
            for (int q2 = 0; q2 < HID / 4; ++q2) {
                float4 a = w1x[q2], b = w1y[q2], c = vb1[q2], d = vw2[q2];
#define STEP(P, AX) {                                              \
                float h0 = px##P * a.x + py##P * b.x + c.x;        \
                float h1 = px##P * a.y + py##P * b.y + c.y;        \
                float h2 = px##P * a.z + py##P * b.z + c.z;        \
                float h3 = px##P * a.w + py##P * b.w + c.w;        \
                h0 = h0 > 0.f ? h0 : 0.f;                          \
                h1 = h1 > 0.f ? h1 : 0.f;                          \
                h2 = h2 > 0.f ? h2 : 0.f;                          \
                h3 = h3 > 0.f ? h3 : 0.f;                          \
                AX.x += h0 * d.x; AX.y += h1 * d.y;                \
                AX.z += h2 * d.z; AX.w += h3 * d.w; }
                STEP(0, A0) STEP(1, A1) STEP(2, A2) STEP(3, A3)
#undef STEP
            }
#define FIN(AX, NP) {                                              \
            float x = ((AX.x + AX.y) + (AX.z + AX.w)) + vb2;       \
            float rr;                                              \
            if (x >= 0.f) { rr = 1.0f / (1.0f + expf(-x)); }       \
            else { float e = expf(x); rr = e / (1.0f + e); }       \
            nxt[NP] = rr; }
            FIN(A0, n0) FIN(A1, n1) FIN(A2, n2) FIN(A3, n3)
#undef FIN
        }
        g_grid.sync();

        float* tmp = cur; cur = nxt; nxt = tmp;
    }

    // ---- final: broadcast batch-0 grid to all 8 batches (float4 + tail) ----
    int nv = (NMAXPIX + 3) >> 2;
    for (int q = gtid; q < nv; q += nthreads) {
        int n = q * 4;
        if (n + 3 < NMAXPIX) {
            float4 v = *(const float4*)(cur + n);
#pragma unroll
            for (int k = 0; k < 8; ++k) *(float4*)(out + (size_t)k * NMAXPIX + n) = v;
        } else {
            for (int m2 = n; m2 < NMAXPIX; ++m2) {
                float v = cur[m2];
#pragma unroll
                for (int k = 0; k < 8; ++k) out[(size_t)k * NMAXPIX + m2] = v;
            }
        }
    }
}

extern "C" void kernel_launch(void* const* d_in, const int* in_sizes, int n_in,
                              void* d_out, int out_size, void* d_ws, size_t ws_size,
                              hipStream_t stream) {
    const float* w1 = (const float*)d_in[0];
    const float* b1 = (const float*)d_in[1];
    const float* w2 = (const float*)d_in[2];
    const float* b2 = (const float*)d_in[3];
    float* out = (float*)d_out;

    const size_t A = (((size_t)NMAXPIX * 4) + 255) & ~(size_t)255;  // one grid buffer
    const size_t SMALL_BYTES = (size_t)4 * STAGE_U32 * 4;            // 4 stages (~720 KB)
    const size_t LIST_BYTES = (size_t)262144 * 4;
    const size_t need = 3 * A + SMALL_BYTES + LIST_BYTES;

    char* base = (ws_size >= need) ? (char*)d_ws : (char*)d_out;  // d_out 33.6MB >= ~14.4MB needed
    float* buf0 = (float*)(base);
    float* buf1 = (float*)(base + A);
    uint32_t* keys = (uint32_t*)(base + 2 * A);
    uint32_t* smallb = (uint32_t*)(base + 3 * A);
    uint32_t* outlist = (uint32_t*)(base + 3 * A + SMALL_BYTES);

    // grid: clamp to guaranteed co-residency (cooperative launch requirement)
    int dev = 0;
    hipGetDevice(&dev);
    int numCU = 0;
    hipDeviceGetAttribute(&numCU, hipDeviceAttributeMultiprocessorCount, dev);
    int maxPerCU = 0;
    hipOccupancyMaxActiveBlocksPerMultiprocessor(&maxPerCU, k_all, 256, 0);
    if (maxPerCU < 1) maxPerCU = 1;
    if (numCU < 1) numCU = 256;
    long long gl = (long long)numCU * (long long)maxPerCU;
    int grid = (gl > 512) ? 512 : (int)gl;

    void* args[] = {(void*)&w1, (void*)&b1, (void*)&w2, (void*)&b2,
                    (void*)&buf0, (void*)&buf1, (void*)&keys, (void*)&smallb,
                    (void*)&outlist, (void*)&out};
    hipLaunchCooperativeKernel((void*)k_all, dim3(grid), dim3(256), args, 0, stream);
}

// Round 8
// 244.950 us; speedup vs baseline: 3.4990x; 3.4990x over previous
//
#include <hip/hip_runtime.h>
#include <stdint.h>

#define HID 256
#define NMAXPIX (1025 * 1025)
#define NREP 8     // histogram replicas, replica-major: hist[rep*NB + bin]
#define NSEG 2048  // selection segments (one wave each; 512 blocks)
#define SELMAX 2112

// per-stage small-buffer layout (u32 units)
#define HISTA_OFF 0          // 8 x 2048
#define HISTB_OFF 16384      // 8 x 2048
#define HISTC_OFF 32768      // 8 x 1024
#define SCAL_OFF  40960      // [0]=pfx1 [1]=rem1 [2]=pfx2 [3]=rem2 [4]=K [5]=t (pad 64)
#define TIC_OFF   41024      // 2048
#define STAGE_U32 43072

// ---------------- MLP eval (single point), float4 LDS weight reads ----------------
__device__ __forceinline__ float mlp_eval4(float wx, float wy,
                                           const float4* __restrict__ w1x,
                                           const float4* __restrict__ w1y,
                                           const float4* __restrict__ vb1,
                                           const float4* __restrict__ vw2, float b2v) {
    const float C0 = (float)(0.5 / 1025.0);
    float px = (wx / 1025.0f + C0) * 2.0f - 1.0f;
    float py = (wy / 1025.0f + C0) * 2.0f - 1.0f;
    float a0 = 0.f, a1 = 0.f, a2 = 0.f, a3 = 0.f;
#pragma unroll 8
    for (int q = 0; q < HID / 4; ++q) {
        float4 a = w1x[q], b = w1y[q], c = vb1[q], d = vw2[q];
        float h0 = px * a.x + py * b.x + c.x;
        float h1 = px * a.y + py * b.y + c.y;
        float h2 = px * a.z + py * b.z + c.z;
        float h3 = px * a.w + py * b.w + c.w;
        h0 = h0 > 0.f ? h0 : 0.f;
        h1 = h1 > 0.f ? h1 : 0.f;
        h2 = h2 > 0.f ? h2 : 0.f;
        h3 = h3 > 0.f ? h3 : 0.f;
        a0 += h0 * d.x;
        a1 += h1 * d.y;
        a2 += h2 * d.z;
        a3 += h3 * d.w;
    }
    float x = ((a0 + a1) + (a2 + a3)) + b2v;
    float r;
    if (x >= 0.f) { r = 1.0f / (1.0f + expf(-x)); }
    else { float e = expf(x); r = e / (1.0f + e); }
    return r;
}

// ---------------- block exclusive scan helper (256 threads) ----------------
__device__ __forceinline__ uint32_t block_exscan_256(uint32_t v, volatile uint32_t* lds4) {
    int lane = threadIdx.x & 63, w = threadIdx.x >> 6;
    uint32_t inc = v;
#pragma unroll
    for (int d = 1; d < 64; d <<= 1) {
        uint32_t o = (uint32_t)__shfl_up((int)inc, d, 64);
        if (lane >= d) inc += o;
    }
    if (lane == 63) lds4[w] = inc;
    __syncthreads();
    uint32_t woff = 0;
    for (int i = 0; i < w; ++i) woff += lds4[i];
    return woff + inc - v;
}

// ---------------- redundant per-block radix scan of a replicated histogram ----------------
// hist built by the PREVIOUS dispatch (implicit barrier). Every block computes the same result.
__device__ void scan_dev(const uint32_t* __restrict__ hist, int NB,
                         uint32_t rem_in, uint32_t prefix_in, int shift,
                         uint32_t* outp, uint32_t* outr,
                         volatile uint32_t* lds4, volatile uint32_t* ldspair) {
    int tid = threadIdx.x;
    int C = NB >> 8;                 // 8 (NB=2048) or 4 (NB=1024)
    int b0 = NB - (tid + 1) * C;     // thread 0 owns top bins
    uint32_t cnts[8];
#pragma unroll
    for (int k = 0; k < 8; ++k) cnts[k] = 0;
    for (int rep = 0; rep < NREP; ++rep) {
        const uint4* p = (const uint4*)(hist + (size_t)rep * NB + b0);
#pragma unroll
        for (int g = 0; g < 2; ++g) {
            if (g * 4 < C) {
                uint4 v = p[g];
                cnts[g * 4 + 0] += v.x;
                cnts[g * 4 + 1] += v.y;
                cnts[g * 4 + 2] += v.z;
                cnts[g * 4 + 3] += v.w;
            }
        }
    }
    uint32_t ssum = 0;
    for (int k = 0; k < C; ++k) ssum += cnts[k];
    uint32_t excl = block_exscan_256(ssum, lds4);
    uint32_t run = excl;
    for (int k = 0; k < C; ++k) {
        uint32_t c = cnts[C - 1 - k];   // descending bin order within thread
        if (rem_in > run && rem_in <= run + c) {
            ldspair[0] = (prefix_in << shift) | (uint32_t)(b0 + C - 1 - k);
            ldspair[1] = rem_in - run;
        }
        run += c;
    }
    __syncthreads();
    *outp = ldspair[0];
    *outr = ldspair[1];
}

// ---------------- eval0 + zero all per-stage buffers (replaces memset dispatch) ----------------
__global__ __launch_bounds__(256) void k_eval0z(const float* __restrict__ w1, const float* __restrict__ b1,
                                                const float* __restrict__ w2, const float* __restrict__ b2,
                                                float* __restrict__ occ, uint32_t* __restrict__ zbuf, int zcount) {
    __shared__ alignas(16) float sw1[2 * HID];
    __shared__ alignas(16) float sb1[HID];
    __shared__ alignas(16) float sw2[HID];
    int tid = threadIdx.x;
    for (int i = tid; i < 2 * HID; i += 256) sw1[i] = w1[i];
    sb1[tid] = b1[tid];
    sw2[tid] = w2[tid];
    __syncthreads();
    int gtid = blockIdx.x * 256 + tid;
    int nthreads = gridDim.x * 256;
    for (int i = gtid; i < zcount; i += nthreads) zbuf[i] = 0;
    for (int n = gtid; n < 65 * 65; n += nthreads) {
        int i = n / 65, j = n % 65;
        occ[n] = mlp_eval4(16.0f * (float)j, 16.0f * (float)i,
                           (const float4*)sw1, (const float4*)(sw1 + HID),
                           (const float4*)sb1, (const float4*)sw2, b2[0]);
    }
}

// ---------------- upsample 2x + key + msb-11 hist (grid-stride; optional 8-batch write) ----------------
__global__ __launch_bounds__(256) void k_upkey(const float* __restrict__ in, int rp,
                                               float* __restrict__ outg, int r, int nb, int bstride,
                                               uint32_t* __restrict__ keys,
                                               uint32_t* __restrict__ histA) {
    __shared__ uint32_t hist[2048];
    int tid = threadIdx.x;
    for (int k = tid; k < 2048; k += 256) hist[k] = 0;
    __syncthreads();
    int N = r * r;
    int lane = tid & 63;
    int gstride = gridDim.x * 256;
    for (int n0 = blockIdx.x * 256; n0 < N; n0 += gstride) {
        int n = n0 + tid;
        bool act = n < N;
        uint32_t key = 0;
        if (act) {
            int i = n / r, j = n % r;
            int i2 = i >> 1, j2 = j >> 1;
            float v;
            if ((i & 1) == 0) {
                if ((j & 1) == 0) {
                    v = in[i2 * rp + j2];
                } else {
                    float a = in[i2 * rp + j2], b = in[i2 * rp + j2 + 1];
                    v = a * 0.5f + b * 0.5f;
                }
            } else {
                if ((j & 1) == 0) {
                    float a = in[i2 * rp + j2], b = in[(i2 + 1) * rp + j2];
                    v = a * 0.5f + b * 0.5f;
                } else {
                    float a = in[i2 * rp + j2],      c = in[i2 * rp + j2 + 1];
                    float b = in[(i2 + 1) * rp + j2], d = in[(i2 + 1) * rp + j2 + 1];
                    float t1 = a * 0.5f + b * 0.5f;
                    float t2 = c * 0.5f + d * 0.5f;
                    v = t1 * 0.5f + t2 * 0.5f;
                }
            }
            for (int k = 0; k < nb; ++k) outg[(size_t)k * bstride + n] = v;
            float unc = -fabsf(v - 0.5f);
            uint32_t u = __float_as_uint(unc);
            key = (u & 0x80000000u) ? ~u : (u | 0x80000000u);
            keys[n] = key;
        }
        uint32_t bin = key >> 21;
        unsigned long long m = __ballot(act);
        if (m) {
            int leader = __ffsll(m) - 1;
            uint32_t lbin = (uint32_t)__shfl((int)bin, leader, 64);
            unsigned long long smk = __ballot(act && bin == lbin);
            if (smk == m) {
                if (lane == leader) atomicAdd(&hist[lbin], (uint32_t)__popcll(m));
            } else if (act) {
                atomicAdd(&hist[bin], 1u);
            }
        }
    }
    __syncthreads();
    uint32_t* myrep = histA + (size_t)(blockIdx.x & (NREP - 1)) * 2048;
    for (int k = tid; k < 2048; k += 256) {
        uint32_t c = hist[k];
        if (c) atomicAdd(&myrep[k], c);
    }
}

// ---------------- filtered histogram pass (scan of prev hist fused in, per block) ----------------
__global__ __launch_bounds__(256) void k_histmid(const uint32_t* __restrict__ keys, int N,
                                                 const uint32_t* __restrict__ prevHist,
                                                 uint32_t* __restrict__ scal,
                                                 int useNpt, uint32_t npt, int scalInIdx, int shift,
                                                 int scalOutIdx,
                                                 int fshift, int bshift, uint32_t bmask,
                                                 uint32_t* __restrict__ outHist, int NBout) {
    __shared__ uint32_t lh[2048];
    __shared__ uint32_t lds4[4];
    __shared__ uint32_t ldspair[2];
    int tid = threadIdx.x, lane = tid & 63;
    uint32_t rem_in = useNpt ? npt : scal[scalInIdx + 1];
    uint32_t pfx_in = useNpt ? 0u  : scal[scalInIdx];
    uint32_t pfx, rem;
    scan_dev(prevHist, 2048, rem_in, pfx_in, shift, &pfx, &rem, lds4, ldspair);
    if (blockIdx.x == 0 && tid == 0) { scal[scalOutIdx] = pfx; scal[scalOutIdx + 1] = rem; }
    for (int k = tid; k < 2048; k += 256) lh[k] = 0;
    __syncthreads();
    int gstride = gridDim.x * 256;
    for (int base = blockIdx.x * 256; base < N; base += gstride) {
        int n = base + tid;
        bool inb = n < N;
        uint32_t key = inb ? keys[n] : 0u;
        bool flt = inb && ((key >> fshift) == pfx);
        uint32_t bin = (key >> bshift) & bmask;
        unsigned long long m = __ballot(flt);
        if (m) {
            int leader = __ffsll(m) - 1;
            uint32_t lbin = (uint32_t)__shfl((int)bin, leader, 64);
            unsigned long long smk = __ballot(flt && bin == lbin);
            if (smk == m) {
                if (lane == leader) atomicAdd(&lh[lbin], (uint32_t)__popcll(m));
            } else if (flt) {
                atomicAdd(&lh[bin], 1u);
            }
        }
    }
    __syncthreads();
    uint32_t* myrep = outHist + (size_t)(blockIdx.x & (NREP - 1)) * NBout;
    for (int k = tid; k < NBout; k += 256) {
        uint32_t c = lh[k];
        if (c) atomicAdd(&myrep[k], c);
    }
}

// ---------------- final scan (K,t) fused + per-segment tie counts ----------------
__global__ __launch_bounds__(256) void k_segcnt(const uint32_t* __restrict__ keys, int N, int seglen,
                                                const uint32_t* __restrict__ histC,
                                                uint32_t* __restrict__ scal,
                                                uint32_t* __restrict__ tic) {
    __shared__ uint32_t lds4[4];
    __shared__ uint32_t ldspair[2];
    int tid = threadIdx.x, lane = tid & 63;
    uint32_t rem2 = scal[3], pfx2 = scal[2];
    uint32_t K, t;
    scan_dev(histC, 1024, rem2, pfx2, 10, &K, &t, lds4, ldspair);
    if (blockIdx.x == 0 && tid == 0) { scal[4] = K; scal[5] = t; }
    int wv = blockIdx.x * 4 + (tid >> 6);
    int s0 = wv * seglen;
    int s1 = s0 + seglen; if (s1 > N) s1 = N;
    uint32_t tcnt = 0;
    for (int base = s0; base < s1; base += 64) {
        int n = base + lane;
        if (n < s1) tcnt += (keys[n] == K) ? 1u : 0u;
    }
#pragma unroll
    for (int d = 32; d; d >>= 1) tcnt += (uint32_t)__shfl_down((int)tcnt, d, 64);
    if (lane == 0) tic[wv] = tcnt;
}

// ---------------- fused select (exact top-k, index-ascending ties) + LDS compact + dense eval ----------------
__global__ __launch_bounds__(256) void k_seleval(const uint32_t* __restrict__ keys, int N, int seglen,
                                                 const uint32_t* __restrict__ scal,
                                                 const uint32_t* __restrict__ tic,
                                                 int r, float stride,
                                                 float* __restrict__ occ, int nb, int bstride,
                                                 const float* __restrict__ w1, const float* __restrict__ b1,
                                                 const float* __restrict__ w2, const float* __restrict__ b2) {
    __shared__ alignas(16) float sw1[2 * HID];
    __shared__ alignas(16) float sb1[HID];
    __shared__ alignas(16) float sw2[HID];
    __shared__ uint32_t selcnt;
    __shared__ uint32_t selidx[SELMAX];
    int tid = threadIdx.x, lane = tid & 63;
    for (int i = tid; i < 2 * HID; i += 256) sw1[i] = w1[i];
    sb1[tid] = b1[tid];
    sw2[tid] = w2[tid];
    if (tid == 0) selcnt = 0;
    __syncthreads();
    uint32_t K = scal[4], t = scal[5];

    // per-wave exclusive tie prefix over segments [0, wv)
    int wv = blockIdx.x * 4 + (tid >> 6);
    uint32_t tp = 0;
    for (int i = lane; i < wv; i += 64) tp += tic[i];
#pragma unroll
    for (int d = 32; d; d >>= 1) tp += (uint32_t)__shfl_down((int)tp, d, 64);
    tp = (uint32_t)__shfl((int)tp, 0, 64);

    uint32_t tie_run = tp;
    int s0 = wv * seglen;
    int s1 = s0 + seglen; if (s1 > N) s1 = N;
    unsigned long long lowmask = (lane == 63) ? ~0ull >> 1 : ((1ull << lane) - 1ull);
    for (int base = s0; base < s1; base += 64) {
        int n = base + lane;
        bool inb = n < s1;
        uint32_t key = inb ? keys[n] : 0u;
        bool gt = inb && (key > K);
        bool tie = inb && (key == K);
        unsigned long long tm = __ballot(tie);
        uint32_t trank = tie_run + (uint32_t)__popcll(tm & lowmask);
        bool sel = gt || (tie && trank < t);
        unsigned long long smk = __ballot(sel);
        if (smk) {
            int leader = __ffsll(smk) - 1;
            uint32_t wbase = 0;
            if (lane == leader) wbase = atomicAdd(&selcnt, (uint32_t)__popcll(smk));
            wbase = (uint32_t)__shfl((int)wbase, leader, 64);
            if (sel) selidx[wbase + (uint32_t)__popcll(smk & lowmask)] = (uint32_t)n;
        }
        tie_run += (uint32_t)__popcll(tm);
    }
    __syncthreads();

    // dense eval: 2 points per thread per iteration (shared weight reads), no divergence
    uint32_t cnt = selcnt;
    float vb2 = b2[0];
    const float4* w1x = (const float4*)sw1;
    const float4* w1y = (const float4*)(sw1 + HID);
    const float4* vb1 = (const float4*)sb1;
    const float4* vw2 = (const float4*)sw2;
    const float C0 = (float)(0.5 / 1025.0);
    for (uint32_t bb = 0; bb < cnt; bb += 512) {
        uint32_t i0 = bb + tid, i1 = bb + tid + 256;
        bool v0 = i0 < cnt, v1 = i1 < cnt;
        int nA = v0 ? (int)selidx[i0] : 0;
        int nB = v1 ? (int)selidx[i1] : 0;
        int iA = nA / r, jA = nA % r;
        int iB = nB / r, jB = nB % r;
        float pxA = ((stride * (float)jA) / 1025.0f + C0) * 2.0f - 1.0f;
        float pyA = ((stride * (float)iA) / 1025.0f + C0) * 2.0f - 1.0f;
        float pxB = ((stride * (float)jB) / 1025.0f + C0) * 2.0f - 1.0f;
        float pyB = ((stride * (float)iB) / 1025.0f + C0) * 2.0f - 1.0f;
        float4 A0 = {0, 0, 0, 0}, A1 = {0, 0, 0, 0};
#pragma unroll 4
        for (int q = 0; q < HID / 4; ++q) {
            float4 a = w1x[q], b = w1y[q], c = vb1[q], d = vw2[q];
            {
                float h0 = pxA * a.x + pyA * b.x + c.x;
                float h1 = pxA * a.y + pyA * b.y + c.y;
                float h2 = pxA * a.z + pyA * b.z + c.z;
                float h3 = pxA * a.w + pyA * b.w + c.w;
                h0 = h0 > 0.f ? h0 : 0.f;
                h1 = h1 > 0.f ? h1 : 0.f;
                h2 = h2 > 0.f ? h2 : 0.f;
                h3 = h3 > 0.f ? h3 : 0.f;
                A0.x += h0 * d.x; A0.y += h1 * d.y;
                A0.z += h2 * d.z; A0.w += h3 * d.w;
            }
            {
                float h0 = pxB * a.x + pyB * b.x + c.x;
                float h1 = pxB * a.y + pyB * b.y + c.y;
                float h2 = pxB * a.z + pyB * b.z + c.z;
                float h3 = pxB * a.w + pyB * b.w + c.w;
                h0 = h0 > 0.f ? h0 : 0.f;
                h1 = h1 > 0.f ? h1 : 0.f;
                h2 = h2 > 0.f ? h2 : 0.f;
                h3 = h3 > 0.f ? h3 : 0.f;
                A1.x += h0 * d.x; A1.y += h1 * d.y;
                A1.z += h2 * d.z; A1.w += h3 * d.w;
            }
        }
        if (v0) {
            float x = ((A0.x + A0.y) + (A0.z + A0.w)) + vb2;
            float rr;
            if (x >= 0.f) { rr = 1.0f / (1.0f + expf(-x)); }
            else { float e = expf(x); rr = e / (1.0f + e); }
            for (int k = 0; k < nb; ++k) occ[(size_t)k * bstride + nA] = rr;
        }
        if (v1) {
            float x = ((A1.x + A1.y) + (A1.z + A1.w)) + vb2;
            float rr;
            if (x >= 0.f) { rr = 1.0f / (1.0f + expf(-x)); }
            else { float e = expf(x); rr = e / (1.0f + e); }
            for (int k = 0; k < nb; ++k) occ[(size_t)k * bstride + nB] = rr;
        }
    }
}

// ---------------- fallback-only broadcast (used when d_ws is too small) ----------------
__global__ __launch_bounds__(256) void k_bcast(const float* __restrict__ src, float* __restrict__ dst, int N) {
    int q = blockIdx.x * 256 + threadIdx.x;
    int n = q * 4;
    if (n + 3 < N) {
        float4 v = *(const float4*)(src + n);
#pragma unroll
        for (int k = 0; k < 8; ++k) *(float4*)(dst + (size_t)k * N + n) = v;
    } else if (n < N) {
        for (int m = n; m < N; ++m) {
            float v = src[m];
#pragma unroll
            for (int k = 0; k < 8; ++k) dst[(size_t)k * N + m] = v;
        }
    }
}

extern "C" void kernel_launch(void* const* d_in, const int* in_sizes, int n_in,
                              void* d_out, int out_size, void* d_ws, size_t ws_size,
                              hipStream_t stream) {
    const float* w1 = (const float*)d_in[0];
    const float* b1 = (const float*)d_in[1];
    const float* w2 = (const float*)d_in[2];
    const float* b2 = (const float*)d_in[3];
    float* out = (float*)d_out;

    const size_t A = (((size_t)NMAXPIX * 4) + 255) & ~(size_t)255;  // one grid buffer
    const size_t SMALL_BYTES = (size_t)4 * STAGE_U32 * 4;            // 4 stages (~690 KB)
    const size_t need = 3 * A + SMALL_BYTES;

    int fused8 = (ws_size >= need);  // stage-4 writes all 8 batches directly only when ws holds scratch
    char* base = fused8 ? (char*)d_ws : (char*)d_out;
    float* buf0 = (float*)(base);
    float* buf1 = (float*)(base + A);
    uint32_t* keys = (uint32_t*)(base + 2 * A);
    uint32_t* smallb = (uint32_t*)(base + 3 * A);

    // dispatch 1: zero all stage buffers + dense 65x65 eval
    k_eval0z<<<dim3(512), dim3(256), 0, stream>>>(w1, b1, w2, b2, buf0, smallb, 4 * STAGE_U32);

    const int resA[5] = {65, 129, 257, 513, 1025};
    const int nptA[5] = {0, 4096, 16384, 65536, 262144};
    float* cur = buf0;
    float* nxt = buf1;
    for (int s = 1; s < 5; ++s) {
        int rp = resA[s - 1], r = resA[s];
        int N = r * r;
        uint32_t npt = (uint32_t)nptA[s];
        uint32_t* sm    = smallb + (size_t)(s - 1) * STAGE_U32;
        uint32_t* histA = sm + HISTA_OFF;
        uint32_t* histB = sm + HISTB_OFF;
        uint32_t* histC = sm + HISTC_OFF;
        uint32_t* scal  = sm + SCAL_OFF;
        uint32_t* tic   = sm + TIC_OFF;
        int nb1 = (N + 255) / 256;
        int nbu = nb1 < 1024 ? nb1 : 1024;
        int seglen = (N + NSEG - 1) / NSEG;
        float stride = 1024.0f / (float)(r - 1);

        int last = (s == 4);
        float* stage_out = (last && fused8) ? out : nxt;
        int nb = (last && fused8) ? 8 : 1;
        int bstride = (last && fused8) ? NMAXPIX : 0;

        k_upkey<<<dim3(nbu), dim3(256), 0, stream>>>(cur, rp, stage_out, r, nb, bstride, keys, histA);
        k_histmid<<<dim3(512), dim3(256), 0, stream>>>(keys, N, histA, scal, 1, npt, 0, 0,
                                                       0, 21, 10, 0x7FFu, histB, 2048);
        k_histmid<<<dim3(512), dim3(256), 0, stream>>>(keys, N, histB, scal, 0, 0u, 0, 11,
                                                       2, 10, 0, 0x3FFu, histC, 1024);
        k_segcnt<<<dim3(NSEG / 4), dim3(256), 0, stream>>>(keys, N, seglen, histC, scal, tic);
        k_seleval<<<dim3(NSEG / 4), dim3(256), 0, stream>>>(keys, N, seglen, scal, tic, r, stride,
                                                            stage_out, nb, bstride, w1, b1, w2, b2);
        if (!(last && fused8)) { float* tmp = cur; cur = nxt; nxt = tmp; }
    }
    if (!fused8) {
        // fallback: scratch lived in d_out; final grid is at cur (= buf0 offset 0)
        k_bcast<<<dim3(((NMAXPIX + 3) / 4 + 255) / 256), dim3(256), 0, stream>>>(cur, out, NMAXPIX);
    }
}